// Round 5
// baseline (401.872 us; speedup 1.0000x reference)
//
#include <hip/hip_runtime.h>
#include <hip/hip_bf16.h>
#include <math.h>

// B=64, H=1024, I=512. out[b,o] = tanh( dot(x[b,:],W_ih[o,:]) + b_ih[o]
//                                       + softmax_h(W_hh[o,:]/tau + g[b,o,:]) . h_prev[b,:] )
//
// R5: quarter-wave rows. R1 vs R0 showed identical dur (362 vs 364) and our
// kernel is absent from top-5 dispatches (< 157 us) -> dur_us likely includes
// ~240 us harness restore/poison; kernel slice ~120 us vs 43 us HBM floor
// (268 MB gumbel stream). One-row-per-wave had a long serial tail (6-deep
// bpermute reduce + tanh) vs only 16 elems/lane of work. Now: 16 lanes per
// row, 4 rows per wave -> 64 elems/lane, reduce depth 4, 4 independent row
// streams per wave for MLP/ILP. Streaming softmax (no max pass) is safe:
// logits bounded in [-3.1, 18.6], exp < 1.2e8, row sum < 1.2e11 (validated:
// absmax 2e-3 vs 2e-2 threshold).

constexpr int B_ = 64;
constexpr int H_ = 1024;
constexpr int I_ = 512;

__global__ __launch_bounds__(256) void reservoir_fused_kernel(
    const float* __restrict__ x_t,         // (B, I)
    const float* __restrict__ h_prev,      // (B, H)
    const float* __restrict__ W_ih,        // (H, I)
    const float* __restrict__ b_ih,        // (H,)
    const float* __restrict__ W_hh,        // (H, H)
    const float* __restrict__ temperature, // scalar
    const float* __restrict__ gumbel,      // (B, H, H)
    float* __restrict__ out)               // (B, H)
{
    const int gtid = blockIdx.x * blockDim.x + threadIdx.x;
    const int lane = threadIdx.x & 63;
    const int q    = lane >> 4;          // quarter 0..3
    const int ql   = lane & 15;          // lane within quarter
    const int row  = (gtid >> 6) * 4 + q;  // global (b*H + o) row, o fastest
    const int b = row >> 10;
    const int o = row & (H_ - 1);

    const float inv_tau = 1.0f / fmaxf(temperature[0], 1e-3f);

    // ---- input contribution: dot(x[b,:], W_ih[o,:]) over I=512, 16 lanes ----
    float ic = 0.0f;
    {
        const float4* x4 = reinterpret_cast<const float4*>(x_t + (size_t)b * I_);
        const float4* w4 = reinterpret_cast<const float4*>(W_ih + (size_t)o * I_);
#pragma unroll
        for (int c = 0; c < 8; ++c) {        // 8 * 16 lanes * 4 = 512
            float4 xv = x4[c * 16 + ql];
            float4 wv = w4[c * 16 + ql];
            ic = fmaf(xv.x, wv.x, ic);
            ic = fmaf(xv.y, wv.y, ic);
            ic = fmaf(xv.z, wv.z, ic);
            ic = fmaf(xv.w, wv.w, ic);
        }
    }

    // ---- streaming exp-sum + weighted sum over the 1024-wide row ----
    float s0 = 0.f, s1 = 0.f, t0 = 0.f, t1 = 0.f;
    {
        const float4* g4 = reinterpret_cast<const float4*>(gumbel) + (size_t)row * (H_ / 4);
        const float4* w4 = reinterpret_cast<const float4*>(W_hh + (size_t)o * H_);
        const float4* h4 = reinterpret_cast<const float4*>(h_prev + (size_t)b * H_);
#pragma unroll 4
        for (int c = 0; c < 16; ++c) {       // 16 * 16 lanes * 4 = 1024
            float4 g = g4[c * 16 + ql];
            float4 w = w4[c * 16 + ql];
            float4 h = h4[c * 16 + ql];
            float e0 = __expf(fmaf(w.x, inv_tau, g.x));
            float e1 = __expf(fmaf(w.y, inv_tau, g.y));
            float e2 = __expf(fmaf(w.z, inv_tau, g.z));
            float e3 = __expf(fmaf(w.w, inv_tau, g.w));
            s0 += e0 + e1;
            s1 += e2 + e3;
            t0 = fmaf(e0, h.x, t0);
            t1 = fmaf(e1, h.y, t1);
            t0 = fmaf(e2, h.z, t0);
            t1 = fmaf(e3, h.w, t1);
        }
    }
    float s = s0 + s1;
    float t = t0 + t1;

    // ---- quarter-wave (16-lane) reductions, depth 4, interleaved ----
#pragma unroll
    for (int off = 8; off > 0; off >>= 1) {
        s  += __shfl_xor(s,  off, 16);
        t  += __shfl_xor(t,  off, 16);
        ic += __shfl_xor(ic, off, 16);
    }

    if (ql == 0) {
        out[row] = tanhf(ic + b_ih[o] + t / s);
    }
}

extern "C" void kernel_launch(void* const* d_in, const int* in_sizes, int n_in,
                              void* d_out, int out_size, void* d_ws, size_t ws_size,
                              hipStream_t stream) {
    const float* x_t    = (const float*)d_in[0];
    const float* h_prev = (const float*)d_in[1];
    const float* W_ih   = (const float*)d_in[2];
    const float* b_ih   = (const float*)d_in[3];
    const float* W_hh   = (const float*)d_in[4];
    const float* temp   = (const float*)d_in[5];
    const float* gum    = (const float*)d_in[6];
    float* out = (float*)d_out;

    // 65536 rows, 4 rows/wave, 4 waves/block -> 4096 blocks
    const int blocks = (B_ * H_) / 16;
    reservoir_fused_kernel<<<blocks, 256, 0, stream>>>(
        x_t, h_prev, W_ih, b_ih, W_hh, temp, gum, out);
}